// Round 6
// baseline (414.219 us; speedup 1.0000x reference)
//
#include <hip/hip_runtime.h>
#include <math.h>

#define B_    64
#define S_    512
#define EMB_  768
#define HID_  512
#define IMG_  2048
#define ATT_  512
#define K_    6
#define HL_   20
#define MS_   (B_ * S_)            // 32768

typedef __attribute__((ext_vector_type(8))) short bf16x8;
typedef __attribute__((ext_vector_type(4))) float f32x4;

__device__ __forceinline__ unsigned short f2b(float f) {
    unsigned int u = __float_as_uint(f);
    u += 0x7fffu + ((u >> 16) & 1u);          // RNE
    return (unsigned short)(u >> 16);
}
__device__ __forceinline__ unsigned int pk_bf16(float lo, float hi) {
    unsigned int r;
    asm volatile("v_cvt_pk_bf16_f32 %0, %1, %2" : "=v"(r) : "v"(lo), "v"(hi));
    return r;
}
__device__ __forceinline__ bf16x8 cvt8(const float4& x, const float4& y) {
    union { unsigned int u[4]; bf16x8 v; } r;
    r.u[0] = pk_bf16(x.x, x.y);
    r.u[1] = pk_bf16(x.z, x.w);
    r.u[2] = pk_bf16(y.x, y.y);
    r.u[3] = pk_bf16(y.z, y.w);
    return r.v;
}

// ---------------------------------------------------------------------------
// prep: z=0..2 -> transpose+cvt of W_e2h / W_mm[:H] / W_a1 ; z=3 -> mask probe
__global__ __launch_bounds__(256)
void prep(const float* __restrict__ W_e2h, const float* __restrict__ W_mm,
          const float* __restrict__ W_a1,
          unsigned short* __restrict__ WtE2H, unsigned short* __restrict__ WtMM,
          unsigned short* __restrict__ WtA1,
          const unsigned char* __restrict__ masks, int* __restrict__ flag) {
    const int z = blockIdx.z;
    if (z == 3) {
        if (blockIdx.x != 0 || blockIdx.y != 0) return;
        __shared__ int found;
        if (threadIdx.x == 0) found = 0;
        __syncthreads();
        for (int i = threadIdx.x; i < 8192; i += 256)
            if ((i & 3) != 0 && masks[i] != 0) found = 1;
        __syncthreads();
        if (threadIdx.x == 0) *flag = found;
        return;
    }
    const float* W;
    unsigned short* Wt;
    int Kd;
    if (z == 0)      { W = W_e2h; Wt = WtE2H; Kd = EMB_; }
    else if (z == 1) { W = W_mm;  Wt = WtMM;  Kd = HID_; }
    else             { W = W_a1;  Wt = WtA1;  Kd = HID_; }
    if ((int)blockIdx.x * 32 >= Kd) return;

    __shared__ float tile[32][33];
    int k0 = blockIdx.x * 32, n0 = blockIdx.y * 32;
    int tx = threadIdx.x & 31, ty = threadIdx.x >> 5;   // 32 x 8
    #pragma unroll
    for (int i = 0; i < 4; ++i)
        tile[ty + i * 8][tx] = W[(size_t)(k0 + ty + i * 8) * HID_ + n0 + tx];
    __syncthreads();
    #pragma unroll
    for (int i = 0; i < 4; ++i)
        Wt[(size_t)(n0 + ty + i * 8) * Kd + k0 + tx] = f2b(tile[tx][ty + i * 8]);
}

// ---------------------------------------------------------------------------
// XCD-chunked bijective block swizzle helper (nwg % 8 == 0).
__device__ __forceinline__ void tile_coords(int N, int& bm, int& bn) {
    const int nwg = gridDim.x;
    const int cpx = nwg >> 3;
    const int lid = ((int)blockIdx.x & 7) * cpx + ((int)blockIdx.x >> 3);
    const int ntl = N >> 7;
    bn = (lid % ntl) << 7;
    bm = (lid / ntl) << 7;
}

// ---------------------------------------------------------------------------
// Barrier-free register-prefetch MFMA GEMM.
// C = act(A[M,K] @ Bt[N,K]^T + bias + row_add), 128x128 tile, 4 waves (2x2),
// 4x4 16x16x32 fragments/wave. Fragments loaded straight from global (no LDS,
// no __syncthreads); two register sets ping-pong so the next K-step's loads
// fly under the current MFMAs. A is fp32 (cvt at use) when AF32.
// SCORE mode: t = tanh(acc + bias) folded into per-slot partial dot with W_a2.
template<bool AF32, int ACT, bool SCORE>
__global__ __launch_bounds__(256, 2)
void gemm_nolds(const void* __restrict__ Av, const unsigned short* __restrict__ Bt,
                const float* __restrict__ bias, const float* __restrict__ row_add,
                int row_div, unsigned short* __restrict__ Co,
                const float* __restrict__ W_a2, float* __restrict__ scores8,
                int M, int N, int Kd) {
    const int tid = threadIdx.x;
    int bm, bn; tile_coords(N, bm, bn);
    const int lane = tid & 63, wid = tid >> 6;
    const int wr = wid >> 1, wc = wid & 1;
    const int fr = lane & 15, hi = lane >> 4;

    const float* pAf[4];
    const unsigned short* pA[4];
    const unsigned short* pB[4];
    #pragma unroll
    for (int m = 0; m < 4; ++m) {
        size_t off = (size_t)(bm + wr * 64 + m * 16 + fr) * Kd + hi * 8;
        pAf[m] = (const float*)Av + off;
        pA[m]  = (const unsigned short*)Av + off;
    }
    #pragma unroll
    for (int n = 0; n < 4; ++n)
        pB[n] = Bt + (size_t)(bn + wc * 64 + n * 16 + fr) * Kd + hi * 8;

    f32x4 acc[4][4] = {};
    bf16x8 a0[4], a1[4], b0[4], b1[4];
    float4 f0[4][2], f1[4][2];

    auto load_set = [&](bf16x8 (&AS)[4], float4 (&FS)[4][2], bf16x8 (&BS)[4], int kc) {
        #pragma unroll
        for (int m = 0; m < 4; ++m) {
            if (AF32) {
                FS[m][0] = *(const float4*)(pAf[m] + kc);
                FS[m][1] = *(const float4*)(pAf[m] + kc + 4);
            } else {
                AS[m] = *(const bf16x8*)(pA[m] + kc);
            }
        }
        #pragma unroll
        for (int n = 0; n < 4; ++n) BS[n] = *(const bf16x8*)(pB[n] + kc);
    };
    auto compute_set = [&](bf16x8 (&AS)[4], float4 (&FS)[4][2], bf16x8 (&BS)[4]) {
        bf16x8 av[4];
        #pragma unroll
        for (int m = 0; m < 4; ++m)
            av[m] = AF32 ? cvt8(FS[m][0], FS[m][1]) : AS[m];
        __builtin_amdgcn_s_setprio(1);
        #pragma unroll
        for (int m = 0; m < 4; ++m)
            #pragma unroll
            for (int n = 0; n < 4; ++n)
                acc[m][n] = __builtin_amdgcn_mfma_f32_16x16x32_bf16(av[m], BS[n], acc[m][n], 0, 0, 0);
        __builtin_amdgcn_s_setprio(0);
    };

    const int half = Kd >> 6;    // double-steps: 12 (K=768) or 8 (K=512)
    load_set(a0, f0, b0, 0);
    load_set(a1, f1, b1, 32);
    for (int i = 0; i < half; ++i) {
        const int kc = i << 6;
        compute_set(a0, f0, b0);
        if (i + 1 < half) load_set(a0, f0, b0, kc + 64);
        compute_set(a1, f1, b1);
        if (i + 1 < half) load_set(a1, f1, b1, kc + 96);
    }

    if (SCORE) {
        float ba[4], wa[4];
        #pragma unroll
        for (int n = 0; n < 4; ++n) {
            int col = bn + wc * 64 + n * 16 + fr;
            ba[n] = bias[col];
            wa[n] = W_a2[col];
        }
        const int slot = (bn >> 7) * 2 + wc;
        #pragma unroll
        for (int m = 0; m < 4; ++m) {
            #pragma unroll
            for (int r = 0; r < 4; ++r) {
                float p = 0.f;
                #pragma unroll
                for (int n = 0; n < 4; ++n)
                    p += tanhf(acc[m][n][r] + ba[n]) * wa[n];
                p += __shfl_xor(p, 1, 64);
                p += __shfl_xor(p, 2, 64);
                p += __shfl_xor(p, 4, 64);
                p += __shfl_xor(p, 8, 64);
                if (fr == 0)
                    scores8[(size_t)slot * M + bm + wr * 64 + m * 16 + hi * 4 + r] = p;
            }
        }
    } else {
        #pragma unroll
        for (int m = 0; m < 4; ++m) {
            #pragma unroll
            for (int n = 0; n < 4; ++n) {
                int col = bn + wc * 64 + n * 16 + fr;
                float badd = bias ? bias[col] : 0.f;
                #pragma unroll
                for (int r = 0; r < 4; ++r) {
                    int row = bm + wr * 64 + m * 16 + hi * 4 + r;
                    float x = acc[m][n][r] + badd;
                    if (row_add) x += row_add[(size_t)(row / row_div) * N + col];
                    if (ACT == 1) x = fmaxf(x, 0.f);
                    Co[(size_t)row * N + col] = f2b(x);
                }
            }
        }
    }
}

// ---------------------------------------------------------------------------
// split-K partial fp32 GEMM: P[z, m, n] = A[m, kz..kz+kps) @ W[.., n]
__global__ __launch_bounds__(256)
void gemm_splitk(const float* __restrict__ A, const float* __restrict__ W,
                 float* __restrict__ P, int M, int N, int Kd, int kps) {
    __shared__ float As[16][68];
    __shared__ float Ws[16][64];
    const int tid = threadIdx.x;
    const int bm = blockIdx.y * 64, bn = blockIdx.x * 64;
    const int ks = blockIdx.z;
    const int tx = tid & 15, ty = tid >> 4;
    const int arow = tid >> 2, akq = tid & 3;
    const int wk = tid >> 4, wnq = tid & 15;

    float acc[4][4] = {};
    const int kbeg = ks * kps, kend = kbeg + kps;

    for (int k0 = kbeg; k0 < kend; k0 += 16) {
        float4 av = *(const float4*)&A[(size_t)(bm + arow) * Kd + k0 + akq * 4];
        float4 wv = *(const float4*)&W[(size_t)(k0 + wk) * N + bn + wnq * 4];
        As[akq * 4 + 0][arow] = av.x;
        As[akq * 4 + 1][arow] = av.y;
        As[akq * 4 + 2][arow] = av.z;
        As[akq * 4 + 3][arow] = av.w;
        *(float4*)&Ws[wk][wnq * 4] = wv;
        __syncthreads();
        #pragma unroll
        for (int kk = 0; kk < 16; ++kk) {
            float4 a4 = *(const float4*)&As[kk][ty * 4];
            float4 b4 = *(const float4*)&Ws[kk][tx * 4];
            float a_[4] = {a4.x, a4.y, a4.z, a4.w};
            float b_[4] = {b4.x, b4.y, b4.z, b4.w};
            #pragma unroll
            for (int i = 0; i < 4; ++i)
                #pragma unroll
                for (int j = 0; j < 4; ++j)
                    acc[i][j] += a_[i] * b_[j];
        }
        __syncthreads();
    }

    float* Pbase = P + (size_t)ks * M * N;
    #pragma unroll
    for (int i = 0; i < 4; ++i) {
        int row = bm + ty * 4 + i;
        float4 v = {acc[i][0], acc[i][1], acc[i][2], acc[i][3]};
        *(float4*)&Pbase[(size_t)row * N + bn + tx * 4] = v;
    }
}

// ---------------------------------------------------------------------------
template<int ACT>
__global__ __launch_bounds__(256)
void reduce_k(const float* __restrict__ P, const float* __restrict__ bias,
              float* __restrict__ C, int MN, int N, int nsplit) {
    int idx = blockIdx.x * 256 + threadIdx.x;
    if (idx >= MN) return;
    float s = 0.f;
    for (int z = 0; z < nsplit; ++z) s += P[(size_t)z * MN + idx];
    if (bias) s += bias[idx & (N - 1)];
    if (ACT == 1) s = fmaxf(s, 0.f);
    C[idx] = s;
}

// ---------------------------------------------------------------------------
// masked softmax over S per batch; input = sum of 8 score slots + b_a2.
__global__ __launch_bounds__(256)
void softmax8(const float* __restrict__ scores8, const float* __restrict__ b_a2,
              const void* __restrict__ masks_raw, const int* __restrict__ flag,
              float* __restrict__ attw) {
    int b = blockIdx.x, tid = threadIdx.x;
    bool isb = (*flag) != 0;
    const unsigned char* mb = (const unsigned char*)masks_raw;
    const int* mi = (const int*)masks_raw;
    int lane = tid & 63, wv = tid >> 6;
    __shared__ float red[4], red2[4];
    float bias = b_a2[0];

    float m = -INFINITY;
    for (int s = tid; s < S_; s += 256) {
        int idx = b * S_ + s;
        float v = bias;
        #pragma unroll
        for (int z = 0; z < 8; ++z) v += scores8[(size_t)z * MS_ + idx];
        bool mk = isb ? (mb[idx] != 0) : (mi[idx] != 0);
        v = mk ? -INFINITY : v;
        attw[idx] = v;
        m = fmaxf(m, v);
    }
    #pragma unroll
    for (int off = 32; off; off >>= 1) m = fmaxf(m, __shfl_down(m, off, 64));
    if (lane == 0) red[wv] = m;
    __syncthreads();
    if (tid == 0) red[0] = fmaxf(fmaxf(red[0], red[1]), fmaxf(red[2], red[3]));
    __syncthreads();
    float Mx = red[0];

    float sum = 0.f;
    for (int s = tid; s < S_; s += 256) {
        int idx = b * S_ + s;
        float e = expf(attw[idx] - Mx);
        attw[idx] = e;
        sum += e;
    }
    #pragma unroll
    for (int off = 32; off; off >>= 1) sum += __shfl_down(sum, off, 64);
    if (lane == 0) red2[wv] = sum;
    __syncthreads();
    if (tid == 0) red2[0] = red2[0] + red2[1] + red2[2] + red2[3];
    __syncthreads();
    float inv = 1.f / red2[0];
    for (int s = tid; s < S_; s += 256) attw[b * S_ + s] *= inv;
}

// ---------------------------------------------------------------------------
// att4[z][b][h] = sum_{s in z-chunk} bf16(mm[b,s,h]) * attw[b,s]   (4 s-chunks)
__global__ __launch_bounds__(256)
void attended4(const unsigned short* __restrict__ mm, const float* __restrict__ attw,
               float* __restrict__ att4) {
    int b = blockIdx.x;
    int h = blockIdx.y * 256 + threadIdx.x;
    int z = blockIdx.z;
    __shared__ float w[128];
    int s0 = z * 128;
    if (threadIdx.x < 128) w[threadIdx.x] = attw[b * S_ + s0 + threadIdx.x];
    __syncthreads();
    float acc = 0.f;
    for (int s = 0; s < 128; ++s)
        acc += __uint_as_float((unsigned int)mm[((size_t)b * S_ + s0 + s) * HID_ + h] << 16) * w[s];
    att4[((size_t)z * B_ + b) * HID_ + h] = acc;
}

// ---------------------------------------------------------------------------
__global__ __launch_bounds__(256)
void hist_avg(const float* __restrict__ ph, const int* __restrict__ hcnt,
              float* __restrict__ havg) {
    int bk = blockIdx.x;
    int cnt = hcnt[bk];
    float denom = (float)(cnt > 1 ? cnt : 1);
    const float* base = ph + (size_t)bk * HL_ * EMB_;
    for (int e = threadIdx.x; e < EMB_; e += 256) {
        float s = 0.f;
        for (int l = 0; l < cnt; ++l) s += base[l * EMB_ + e];
        havg[bk * EMB_ + e] = s / denom;
    }
}

// ---------------------------------------------------------------------------
// combine_all: reduce split-K partials of hproj(8) and sep0(16), add biases,
// relu/merge per reference, L2-normalize, dot with attended (sum of 4 chunks).
__global__ __launch_bounds__(256)
void combine_all(const float* __restrict__ skA, const float* __restrict__ skB,
                 const float* __restrict__ b_hist, const float* __restrict__ b_sep,
                 const int* __restrict__ hcnt, const float* __restrict__ att4,
                 float* __restrict__ out) {
    const int MNA = B_ * K_ * HID_;
    int bk = blockIdx.x, tid = threadIdx.x;
    int b = bk / K_;
    int cnt = hcnt[bk];
    float sq = 0.f, dt = 0.f;
    #pragma unroll
    for (int i = 0; i < HID_ / 256; ++i) {
        int h = tid + i * 256;
        size_t idx = (size_t)bk * HID_ + h;
        float hp = b_hist[h];
        #pragma unroll
        for (int z = 0; z < 8; ++z) hp += skA[(size_t)z * MNA + idx];
        hp = fmaxf(hp, 0.f);
        float sp = b_sep[h];
        #pragma unroll
        for (int z = 0; z < 16; ++z) sp += skB[(size_t)z * MNA + idx];
        float v = sp + (cnt > 0 ? hp : 0.f);
        v = fmaxf(v, 0.f);
        float at = 0.f;
        #pragma unroll
        for (int z = 0; z < 4; ++z) at += att4[((size_t)z * B_ + b) * HID_ + h];
        sq += v * v;
        dt += v * at;
    }
    #pragma unroll
    for (int off = 32; off; off >>= 1) {
        sq += __shfl_down(sq, off, 64);
        dt += __shfl_down(dt, off, 64);
    }
    __shared__ float rs[4], rd[4];
    int lane = tid & 63, wv = tid >> 6;
    if (lane == 0) { rs[wv] = sq; rd[wv] = dt; }
    __syncthreads();
    if (tid == 0) {
        float Sq = rs[0] + rs[1] + rs[2] + rs[3];
        float Dt = rd[0] + rd[1] + rd[2] + rd[3];
        float norm = fmaxf(sqrtf(Sq), 1e-12f);
        out[bk] = Dt / norm;
    }
}

// ---------------------------------------------------------------------------
extern "C" void kernel_launch(void* const* d_in, const int* in_sizes, int n_in,
                              void* d_out, int out_size, void* d_ws, size_t ws_size,
                              hipStream_t stream) {
    const float* reps     = (const float*)d_in[0];
    const float* sep_imgs = (const float*)d_in[2];
    const float* vctx     = (const float*)d_in[3];
    const float* phist    = (const float*)d_in[4];
    const int*   hcnt     = (const int*)d_in[5];
    const void*  masks    = d_in[6];
    const float* W_sep = (const float*)d_in[7];
    const float* b_sep = (const float*)d_in[8];
    const float* W_e2h = (const float*)d_in[9];
    const float* b_e2h = (const float*)d_in[10];
    const float* W_hist = (const float*)d_in[11];
    const float* b_hist = (const float*)d_in[12];
    const float* W_ctx = (const float*)d_in[13];
    const float* b_ctx = (const float*)d_in[14];
    const float* W_mm = (const float*)d_in[15];
    const float* b_mm = (const float*)d_in[16];
    const float* W_a1 = (const float*)d_in[17];
    const float* b_a1 = (const float*)d_in[18];
    const float* W_a2 = (const float*)d_in[19];
    const float* b_a2 = (const float*)d_in[20];
    float* out = (float*)d_out;

    const size_t MS = (size_t)MS_;
    const int MNA = B_ * K_ * HID_;   // 196608

    // ---- workspace layout ----
    unsigned short* actA  = (unsigned short*)d_ws;          // [MS*HID] input_reps bf16
    unsigned short* actB  = actA + MS * HID_;               // [MS*HID] mm bf16
    unsigned short* WtE2H = actB + MS * HID_;               // [512*768]
    unsigned short* WtMM  = WtE2H + (size_t)EMB_ * HID_;    // [512*512]
    unsigned short* WtA1  = WtMM + (size_t)HID_ * HID_;     // [512*512]
    float* skC    = (float*)(WtA1 + (size_t)HID_ * HID_);   // [64 * 64*512] ctx splits
    float* skA    = skC + (size_t)64 * B_ * HID_;           // [8  * 384*512] hproj splits
    float* skB    = skA + (size_t)8 * MNA;                  // [16 * 384*512] sep0 splits
    float* scores8 = skB + (size_t)16 * MNA;                // [8 * MS]
    float* attw   = scores8 + 8 * MS;                       // [B,S]
    float* att4   = attw + MS;                              // [4,B,HID]
    float* ctx    = att4 + (size_t)4 * B_ * HID_;           // [B,HID]
    float* ctx2   = ctx + B_ * HID_;                        // [B,HID]
    float* havg   = ctx2 + B_ * HID_;                       // [B*K,EMB]
    int*   flag   = (int*)(havg + (size_t)B_ * K_ * EMB_);

    // 1. prep: weight transposes (bf16) + mask dtype probe
    prep<<<dim3(EMB_ / 32, HID_ / 32, 4), 256, 0, stream>>>(
        W_e2h, W_mm, W_a1, WtE2H, WtMM, WtA1, (const unsigned char*)masks, flag);

    // 2. ctx = relu(visual_context @ W_ctx + b_ctx)   [64,512], K=12288, split-K 64
    {
        const int nsp = 64, kps = (K_ * IMG_) / nsp;
        gemm_splitk<<<dim3(8, 1, nsp), 256, 0, stream>>>(vctx, W_ctx, skC,
                                                         B_, HID_, K_ * IMG_, kps);
        reduce_k<1><<<(B_ * HID_ + 255) / 256, 256, 0, stream>>>(skC, b_ctx, ctx,
                                                                 B_ * HID_, HID_, nsp);
    }
    // 3. ctx2 = ctx @ W_mm[H:,:] + b_mm               [64,512], K=512, split-K 8
    {
        const int nsp = 8, kps = HID_ / nsp;
        gemm_splitk<<<dim3(8, 1, nsp), 256, 0, stream>>>(ctx, W_mm + (size_t)HID_ * HID_,
                                                         skC, B_, HID_, HID_, kps);
        reduce_k<0><<<(B_ * HID_ + 255) / 256, 256, 0, stream>>>(skC, b_mm, ctx2,
                                                                 B_ * HID_, HID_, nsp);
    }

    const int big_grid = (MS_ / 128) * (HID_ / 128);   // 1024, % 8 == 0
    // 4. input_reps = relu(reps @ W_e2h + b_e2h)   fp32-in, no-LDS MFMA -> bf16 actA
    gemm_nolds<true, 1, false><<<big_grid, 256, 0, stream>>>(
        reps, WtE2H, b_e2h, nullptr, 1, actA, nullptr, nullptr, MS_, HID_, EMB_);
    // 5. mm = relu(input_reps @ W_mm[:H] + ctx2[b]) -> bf16 actB
    gemm_nolds<false, 1, false><<<big_grid, 256, 0, stream>>>(
        actA, WtMM, nullptr, ctx2, S_, actB, nullptr, nullptr, MS_, HID_, HID_);
    // 6. fused t=tanh(mm@W_a1+b_a1); scores8 = partial dots with W_a2
    gemm_nolds<false, 0, true><<<big_grid, 256, 0, stream>>>(
        actB, WtA1, b_a1, nullptr, 1, actA, W_a2, scores8, MS_, ATT_, HID_);
    // 7. masked softmax (sums 8 slots + b_a2) -> attw
    softmax8<<<B_, 256, 0, stream>>>(scores8, b_a2, masks, flag, attw);
    // 8. attended partials over 4 s-chunks
    attended4<<<dim3(B_, HID_ / 256, 4), 256, 0, stream>>>(actB, attw, att4);
    // 9. havg
    hist_avg<<<B_ * K_, 256, 0, stream>>>(phist, hcnt, havg);
    // 10. hproj partials                              [384,512], K=768, split-K 8
    gemm_splitk<<<dim3(8, 6, 8), 256, 0, stream>>>(havg, W_hist, skA,
                                                   B_ * K_, HID_, EMB_, EMB_ / 8);
    // 11. sep0 partials                               [384,512], K=2048, split-K 16
    gemm_splitk<<<dim3(8, 6, 16), 256, 0, stream>>>(sep_imgs, W_sep, skB,
                                                    B_ * K_, HID_, IMG_, IMG_ / 16);
    // 12. combine: reduce partials, relu/merge, L2-normalize, dot -> out [384]
    combine_all<<<B_ * K_, 256, 0, stream>>>(skA, skB, b_hist, b_sep, hcnt,
                                             att4, out);
}

// Round 7
// 261.287 us; speedup vs baseline: 1.5853x; 1.5853x over previous
//
#include <hip/hip_runtime.h>
#include <math.h>

#define B_    64
#define S_    512
#define EMB_  768
#define HID_  512
#define IMG_  2048
#define ATT_  512
#define K_    6
#define HL_   20
#define MS_   (B_ * S_)            // 32768

typedef __attribute__((ext_vector_type(8))) short bf16x8;
typedef __attribute__((ext_vector_type(4))) float f32x4;

__device__ __forceinline__ unsigned short f2b(float f) {
    unsigned int u = __float_as_uint(f);
    u += 0x7fffu + ((u >> 16) & 1u);          // RNE
    return (unsigned short)(u >> 16);
}
__device__ __forceinline__ unsigned int pk_bf16(float lo, float hi) {
    unsigned int r;
    asm volatile("v_cvt_pk_bf16_f32 %0, %1, %2" : "=v"(r) : "v"(lo), "v"(hi));
    return r;
}

#define GLD_LDS16(gp, lp)                                                        \
    __builtin_amdgcn_global_load_lds(                                            \
        (const __attribute__((address_space(1))) void*)(gp),                     \
        (__attribute__((address_space(3))) void*)(lp), 16, 0, 0)

// ---------------------------------------------------------------------------
// prep: z=0..2 -> transpose+cvt of W_e2h / W_mm[:H] / W_a1 ; z=3 -> mask probe
__global__ __launch_bounds__(256)
void prep(const float* __restrict__ W_e2h, const float* __restrict__ W_mm,
          const float* __restrict__ W_a1,
          unsigned short* __restrict__ WtE2H, unsigned short* __restrict__ WtMM,
          unsigned short* __restrict__ WtA1,
          const unsigned char* __restrict__ masks, int* __restrict__ flag) {
    const int z = blockIdx.z;
    if (z == 3) {
        if (blockIdx.x != 0 || blockIdx.y != 0) return;
        __shared__ int found;
        if (threadIdx.x == 0) found = 0;
        __syncthreads();
        for (int i = threadIdx.x; i < 8192; i += 256)
            if ((i & 3) != 0 && masks[i] != 0) found = 1;
        __syncthreads();
        if (threadIdx.x == 0) *flag = found;
        return;
    }
    const float* W;
    unsigned short* Wt;
    int Kd;
    if (z == 0)      { W = W_e2h; Wt = WtE2H; Kd = EMB_; }
    else if (z == 1) { W = W_mm;  Wt = WtMM;  Kd = HID_; }
    else             { W = W_a1;  Wt = WtA1;  Kd = HID_; }
    if ((int)blockIdx.x * 32 >= Kd) return;

    __shared__ float tile[32][33];
    int k0 = blockIdx.x * 32, n0 = blockIdx.y * 32;
    int tx = threadIdx.x & 31, ty = threadIdx.x >> 5;   // 32 x 8
    #pragma unroll
    for (int i = 0; i < 4; ++i)
        tile[ty + i * 8][tx] = W[(size_t)(k0 + ty + i * 8) * HID_ + n0 + tx];
    __syncthreads();
    #pragma unroll
    for (int i = 0; i < 4; ++i)
        Wt[(size_t)(n0 + ty + i * 8) * Kd + k0 + tx] = f2b(tile[tx][ty + i * 8]);
}

// ---------------------------------------------------------------------------
// XCD-chunked bijective block swizzle helper (nwg % 8 == 0).
__device__ __forceinline__ void tile_coords(int N, int& bm, int& bn) {
    const int nwg = gridDim.x;
    const int cpx = nwg >> 3;
    const int lid = ((int)blockIdx.x & 7) * cpx + ((int)blockIdx.x >> 3);
    const int ntl = N >> 7;
    bn = (lid % ntl) << 7;
    bm = (lid / ntl) << 7;
}

// ---------------------------------------------------------------------------
// Counted-vmcnt pipelined MFMA GEMM (T4): 128x128 tile, BK=64, double-buffered
// LDS, XOR-swizzled layout, RAW s_barrier with hand-counted s_waitcnt so the
// prefetched global_load_lds stay in flight across barriers (never drain to 0
// mid-loop). 4 waves (2x2), 4x4 16x16x32 fragments.
// AF32: A is fp32, reg-staged (global->reg->cvt->ds_write). Else A bf16 via
// global_load_lds. SCORE: tanh+dot-W_a2 epilogue writing per-slot partials.
template<bool AF32, int ACT, bool SCORE>
__global__ __launch_bounds__(256)
void gemm_pipe(const void* __restrict__ Av, const unsigned short* __restrict__ Bt,
               const float* __restrict__ bias, const float* __restrict__ row_add,
               int row_div, unsigned short* __restrict__ Co,
               const float* __restrict__ W_a2, float* __restrict__ scores8,
               int M, int N, int Kd) {
    __shared__ unsigned short Als[2][128 * 64];
    __shared__ unsigned short Bls[2][128 * 64];
    const int tid = threadIdx.x;
    int bm, bn; tile_coords(N, bm, bn);
    const int lane = tid & 63, wid = tid >> 6;
    const int wr = wid >> 1, wc = wid & 1;
    const int fr = lane & 15, hi = lane >> 4;

    const unsigned short* Ab = (const unsigned short*)Av;
    const float* Af = (const float*)Av;

    f32x4 acc[4][4] = {};
    int srow[4], lcol[4], scol[4];
    #pragma unroll
    for (int c = 0; c < 4; ++c) {
        int g = c * 256 + tid;
        srow[c] = g >> 3;
        lcol[c] = g & 7;
        scol[c] = lcol[c] ^ (srow[c] & 7);
    }

    float4 ra[8];   // fp32-A staging regs (2 float4 per chunk)

    // --- staging helpers ------------------------------------------------
    auto stageA_lds = [&](int t, int buf) {       // bf16 A via gld_lds
        #pragma unroll
        for (int c = 0; c < 4; ++c) {
            int g = c * 256 + tid;
            GLD_LDS16(Ab + (size_t)(bm + srow[c]) * Kd + t * 64 + scol[c] * 8,
                      &Als[buf][g * 8]);
        }
    };
    auto stageB_lds = [&](int t, int buf) {
        #pragma unroll
        for (int c = 0; c < 4; ++c) {
            int g = c * 256 + tid;
            GLD_LDS16(Bt + (size_t)(bn + srow[c]) * Kd + t * 64 + scol[c] * 8,
                      &Bls[buf][g * 8]);
        }
    };
    auto loadA_regs = [&](int t) {                // fp32 A -> regs (8 loads)
        #pragma unroll
        for (int c = 0; c < 4; ++c) {
            const float* p = Af + (size_t)(bm + srow[c]) * Kd + t * 64 + lcol[c] * 8;
            ra[2 * c]     = *(const float4*)p;
            ra[2 * c + 1] = *(const float4*)(p + 4);
        }
    };
    auto writeA = [&](int buf) {                  // cvt + swizzled ds_write
        #pragma unroll
        for (int c = 0; c < 4; ++c) {
            uint4 u;
            u.x = pk_bf16(ra[2*c].x,   ra[2*c].y);
            u.y = pk_bf16(ra[2*c].z,   ra[2*c].w);
            u.z = pk_bf16(ra[2*c+1].x, ra[2*c+1].y);
            u.w = pk_bf16(ra[2*c+1].z, ra[2*c+1].w);
            *(uint4*)&Als[buf][(srow[c] * 8 + scol[c]) * 8] = u;
        }
    };
    auto compute = [&](int buf) {
        #pragma unroll
        for (int kk = 0; kk < 2; ++kk) {
            bf16x8 af[4], bv[4];
            #pragma unroll
            for (int m = 0; m < 4; ++m) {
                int row = wr * 64 + m * 16 + fr;
                int sc = (kk * 4 + hi) ^ (fr & 7);
                af[m] = *(const bf16x8*)&Als[buf][row * 64 + sc * 8];
            }
            #pragma unroll
            for (int n = 0; n < 4; ++n) {
                int row = wc * 64 + n * 16 + fr;
                int sc = (kk * 4 + hi) ^ (fr & 7);
                bv[n] = *(const bf16x8*)&Bls[buf][row * 64 + sc * 8];
            }
            #pragma unroll
            for (int m = 0; m < 4; ++m)
                #pragma unroll
                for (int n = 0; n < 4; ++n)
                    acc[m][n] = __builtin_amdgcn_mfma_f32_16x16x32_bf16(af[m], bv[n], acc[m][n], 0, 0, 0);
        }
    };

    const int nt = Kd >> 6;

    // --- prologue: tile 0 ------------------------------------------------
    if constexpr (AF32) {
        loadA_regs(0);             // 8 reg loads
        stageB_lds(0, 0);          // 4 gld_lds (stay outstanding)
        writeA(0);                 // compiler inserts counted vmcnt for ra
    } else {
        stageA_lds(0, 0);
        stageB_lds(0, 0);          // 8 outstanding
    }

    // --- main loop --------------------------------------------------------
    for (int t = 0; t < nt; ++t) {
        const int buf = t & 1;
        const bool pf = (t + 1 < nt);
        if (pf) {
            if constexpr (AF32) {
                loadA_regs(t + 1);             // 8 (oldest of new batch)
                stageB_lds(t + 1, buf ^ 1);    // 4
            } else {
                stageA_lds(t + 1, buf ^ 1);    // 4
                stageB_lds(t + 1, buf ^ 1);    // 4
            }
        }
        __builtin_amdgcn_sched_barrier(0);
        if (pf) {
            if constexpr (AF32) asm volatile("s_waitcnt vmcnt(12)" ::: "memory");
            else                asm volatile("s_waitcnt vmcnt(8)"  ::: "memory");
        } else {
            asm volatile("s_waitcnt vmcnt(0)" ::: "memory");
        }
        __builtin_amdgcn_s_barrier();
        __builtin_amdgcn_sched_barrier(0);

        compute(buf);

        if constexpr (AF32) {
            if (pf) {
                writeA(buf ^ 1);   // compiler waits counted vmcnt for ra
                asm volatile("s_waitcnt lgkmcnt(0)" ::: "memory");
            }
        }
        __builtin_amdgcn_sched_barrier(0);
        __builtin_amdgcn_s_barrier();
    }

    // --- epilogue ---------------------------------------------------------
    if (SCORE) {
        float ba[4], wa[4];
        #pragma unroll
        for (int n = 0; n < 4; ++n) {
            int col = bn + wc * 64 + n * 16 + fr;
            ba[n] = bias[col];
            wa[n] = W_a2[col];
        }
        const int slot = (bn >> 7) * 2 + wc;
        #pragma unroll
        for (int m = 0; m < 4; ++m) {
            #pragma unroll
            for (int r = 0; r < 4; ++r) {
                float p = 0.f;
                #pragma unroll
                for (int n = 0; n < 4; ++n)
                    p += tanhf(acc[m][n][r] + ba[n]) * wa[n];
                p += __shfl_xor(p, 1, 64);
                p += __shfl_xor(p, 2, 64);
                p += __shfl_xor(p, 4, 64);
                p += __shfl_xor(p, 8, 64);
                if (fr == 0)
                    scores8[(size_t)slot * M + bm + wr * 64 + m * 16 + hi * 4 + r] = p;
            }
        }
    } else {
        #pragma unroll
        for (int m = 0; m < 4; ++m) {
            #pragma unroll
            for (int n = 0; n < 4; ++n) {
                int col = bn + wc * 64 + n * 16 + fr;
                float badd = bias ? bias[col] : 0.f;
                #pragma unroll
                for (int r = 0; r < 4; ++r) {
                    int row = bm + wr * 64 + m * 16 + hi * 4 + r;
                    float x = acc[m][n][r] + badd;
                    if (row_add) x += row_add[(size_t)(row / row_div) * N + col];
                    if (ACT == 1) x = fmaxf(x, 0.f);
                    Co[(size_t)row * N + col] = f2b(x);
                }
            }
        }
    }
}

// ---------------------------------------------------------------------------
// split-K partial fp32 GEMM: P[z, m, n] = A[m, kz..kz+kps) @ W[.., n]
__global__ __launch_bounds__(256)
void gemm_splitk(const float* __restrict__ A, const float* __restrict__ W,
                 float* __restrict__ P, int M, int N, int Kd, int kps) {
    __shared__ float As[16][68];
    __shared__ float Ws[16][64];
    const int tid = threadIdx.x;
    const int bm = blockIdx.y * 64, bn = blockIdx.x * 64;
    const int ks = blockIdx.z;
    const int tx = tid & 15, ty = tid >> 4;
    const int arow = tid >> 2, akq = tid & 3;
    const int wk = tid >> 4, wnq = tid & 15;

    float acc[4][4] = {};
    const int kbeg = ks * kps, kend = kbeg + kps;

    for (int k0 = kbeg; k0 < kend; k0 += 16) {
        float4 av = *(const float4*)&A[(size_t)(bm + arow) * Kd + k0 + akq * 4];
        float4 wv = *(const float4*)&W[(size_t)(k0 + wk) * N + bn + wnq * 4];
        As[akq * 4 + 0][arow] = av.x;
        As[akq * 4 + 1][arow] = av.y;
        As[akq * 4 + 2][arow] = av.z;
        As[akq * 4 + 3][arow] = av.w;
        *(float4*)&Ws[wk][wnq * 4] = wv;
        __syncthreads();
        #pragma unroll
        for (int kk = 0; kk < 16; ++kk) {
            float4 a4 = *(const float4*)&As[kk][ty * 4];
            float4 b4 = *(const float4*)&Ws[kk][tx * 4];
            float a_[4] = {a4.x, a4.y, a4.z, a4.w};
            float b_[4] = {b4.x, b4.y, b4.z, b4.w};
            #pragma unroll
            for (int i = 0; i < 4; ++i)
                #pragma unroll
                for (int j = 0; j < 4; ++j)
                    acc[i][j] += a_[i] * b_[j];
        }
        __syncthreads();
    }

    float* Pbase = P + (size_t)ks * M * N;
    #pragma unroll
    for (int i = 0; i < 4; ++i) {
        int row = bm + ty * 4 + i;
        float4 v = {acc[i][0], acc[i][1], acc[i][2], acc[i][3]};
        *(float4*)&Pbase[(size_t)row * N + bn + tx * 4] = v;
    }
}

// ---------------------------------------------------------------------------
template<int ACT>
__global__ __launch_bounds__(256)
void reduce_k(const float* __restrict__ P, const float* __restrict__ bias,
              float* __restrict__ C, int MN, int N, int nsplit) {
    int idx = blockIdx.x * 256 + threadIdx.x;
    if (idx >= MN) return;
    float s = 0.f;
    for (int z = 0; z < nsplit; ++z) s += P[(size_t)z * MN + idx];
    if (bias) s += bias[idx & (N - 1)];
    if (ACT == 1) s = fmaxf(s, 0.f);
    C[idx] = s;
}

// ---------------------------------------------------------------------------
// masked softmax over S per batch; input = sum of 8 score slots + b_a2.
__global__ __launch_bounds__(256)
void softmax8(const float* __restrict__ scores8, const float* __restrict__ b_a2,
              const void* __restrict__ masks_raw, const int* __restrict__ flag,
              float* __restrict__ attw) {
    int b = blockIdx.x, tid = threadIdx.x;
    bool isb = (*flag) != 0;
    const unsigned char* mb = (const unsigned char*)masks_raw;
    const int* mi = (const int*)masks_raw;
    int lane = tid & 63, wv = tid >> 6;
    __shared__ float red[4], red2[4];
    float bias = b_a2[0];

    float m = -INFINITY;
    for (int s = tid; s < S_; s += 256) {
        int idx = b * S_ + s;
        float v = bias;
        #pragma unroll
        for (int z = 0; z < 8; ++z) v += scores8[(size_t)z * MS_ + idx];
        bool mk = isb ? (mb[idx] != 0) : (mi[idx] != 0);
        v = mk ? -INFINITY : v;
        attw[idx] = v;
        m = fmaxf(m, v);
    }
    #pragma unroll
    for (int off = 32; off; off >>= 1) m = fmaxf(m, __shfl_down(m, off, 64));
    if (lane == 0) red[wv] = m;
    __syncthreads();
    if (tid == 0) red[0] = fmaxf(fmaxf(red[0], red[1]), fmaxf(red[2], red[3]));
    __syncthreads();
    float Mx = red[0];

    float sum = 0.f;
    for (int s = tid; s < S_; s += 256) {
        int idx = b * S_ + s;
        float e = expf(attw[idx] - Mx);
        attw[idx] = e;
        sum += e;
    }
    #pragma unroll
    for (int off = 32; off; off >>= 1) sum += __shfl_down(sum, off, 64);
    if (lane == 0) red2[wv] = sum;
    __syncthreads();
    if (tid == 0) red2[0] = red2[0] + red2[1] + red2[2] + red2[3];
    __syncthreads();
    float inv = 1.f / red2[0];
    for (int s = tid; s < S_; s += 256) attw[b * S_ + s] *= inv;
}

// ---------------------------------------------------------------------------
// att4[z][b][h] = sum_{s in z-chunk} bf16(mm[b,s,h]) * attw[b,s]   (4 s-chunks)
__global__ __launch_bounds__(256)
void attended4(const unsigned short* __restrict__ mm, const float* __restrict__ attw,
               float* __restrict__ att4) {
    int b = blockIdx.x;
    int h = blockIdx.y * 256 + threadIdx.x;
    int z = blockIdx.z;
    __shared__ float w[128];
    int s0 = z * 128;
    if (threadIdx.x < 128) w[threadIdx.x] = attw[b * S_ + s0 + threadIdx.x];
    __syncthreads();
    float acc = 0.f;
    for (int s = 0; s < 128; ++s)
        acc += __uint_as_float((unsigned int)mm[((size_t)b * S_ + s0 + s) * HID_ + h] << 16) * w[s];
    att4[((size_t)z * B_ + b) * HID_ + h] = acc;
}

// ---------------------------------------------------------------------------
__global__ __launch_bounds__(256)
void hist_avg(const float* __restrict__ ph, const int* __restrict__ hcnt,
              float* __restrict__ havg) {
    int bk = blockIdx.x;
    int cnt = hcnt[bk];
    float denom = (float)(cnt > 1 ? cnt : 1);
    const float* base = ph + (size_t)bk * HL_ * EMB_;
    for (int e = threadIdx.x; e < EMB_; e += 256) {
        float s = 0.f;
        for (int l = 0; l < cnt; ++l) s += base[l * EMB_ + e];
        havg[bk * EMB_ + e] = s / denom;
    }
}

// ---------------------------------------------------------------------------
// combine_all: reduce split-K partials of hproj(8) and sep0(16), add biases,
// relu/merge per reference, L2-normalize, dot with attended (sum of 4 chunks).
__global__ __launch_bounds__(256)
void combine_all(const float* __restrict__ skA, const float* __restrict__ skB,
                 const float* __restrict__ b_hist, const float* __restrict__ b_sep,
                 const int* __restrict__ hcnt, const float* __restrict__ att4,
                 float* __restrict__ out) {
    const int MNA = B_ * K_ * HID_;
    int bk = blockIdx.x, tid = threadIdx.x;
    int b = bk / K_;
    int cnt = hcnt[bk];
    float sq = 0.f, dt = 0.f;
    #pragma unroll
    for (int i = 0; i < HID_ / 256; ++i) {
        int h = tid + i * 256;
        size_t idx = (size_t)bk * HID_ + h;
        float hp = b_hist[h];
        #pragma unroll
        for (int z = 0; z < 8; ++z) hp += skA[(size_t)z * MNA + idx];
        hp = fmaxf(hp, 0.f);
        float sp = b_sep[h];
        #pragma unroll
        for (int z = 0; z < 16; ++z) sp += skB[(size_t)z * MNA + idx];
        float v = sp + (cnt > 0 ? hp : 0.f);
        v = fmaxf(v, 0.f);
        float at = 0.f;
        #pragma unroll
        for (int z = 0; z < 4; ++z) at += att4[((size_t)z * B_ + b) * HID_ + h];
        sq += v * v;
        dt += v * at;
    }
    #pragma unroll
    for (int off = 32; off; off >>= 1) {
        sq += __shfl_down(sq, off, 64);
        dt += __shfl_down(dt, off, 64);
    }
    __shared__ float rs[4], rd[4];
    int lane = tid & 63, wv = tid >> 6;
    if (lane == 0) { rs[wv] = sq; rd[wv] = dt; }
    __syncthreads();
    if (tid == 0) {
        float Sq = rs[0] + rs[1] + rs[2] + rs[3];
        float Dt = rd[0] + rd[1] + rd[2] + rd[3];
        float norm = fmaxf(sqrtf(Sq), 1e-12f);
        out[bk] = Dt / norm;
    }
}

// ---------------------------------------------------------------------------
extern "C" void kernel_launch(void* const* d_in, const int* in_sizes, int n_in,
                              void* d_out, int out_size, void* d_ws, size_t ws_size,
                              hipStream_t stream) {
    const float* reps     = (const float*)d_in[0];
    const float* sep_imgs = (const float*)d_in[2];
    const float* vctx     = (const float*)d_in[3];
    const float* phist    = (const float*)d_in[4];
    const int*   hcnt     = (const int*)d_in[5];
    const void*  masks    = d_in[6];
    const float* W_sep = (const float*)d_in[7];
    const float* b_sep = (const float*)d_in[8];
    const float* W_e2h = (const float*)d_in[9];
    const float* b_e2h = (const float*)d_in[10];
    const float* W_hist = (const float*)d_in[11];
    const float* b_hist = (const float*)d_in[12];
    const float* W_ctx = (const float*)d_in[13];
    const float* b_ctx = (const float*)d_in[14];
    const float* W_mm = (const float*)d_in[15];
    const float* b_mm = (const float*)d_in[16];
    const float* W_a1 = (const float*)d_in[17];
    const float* b_a1 = (const float*)d_in[18];
    const float* W_a2 = (const float*)d_in[19];
    const float* b_a2 = (const float*)d_in[20];
    float* out = (float*)d_out;

    const size_t MS = (size_t)MS_;
    const int MNA = B_ * K_ * HID_;   // 196608

    // ---- workspace layout ----
    unsigned short* actA  = (unsigned short*)d_ws;          // [MS*HID] input_reps bf16
    unsigned short* actB  = actA + MS * HID_;               // [MS*HID] mm bf16
    unsigned short* WtE2H = actB + MS * HID_;               // [512*768]
    unsigned short* WtMM  = WtE2H + (size_t)EMB_ * HID_;    // [512*512]
    unsigned short* WtA1  = WtMM + (size_t)HID_ * HID_;     // [512*512]
    float* skC    = (float*)(WtA1 + (size_t)HID_ * HID_);   // [64 * 64*512] ctx splits
    float* skA    = skC + (size_t)64 * B_ * HID_;           // [8  * 384*512] hproj splits
    float* skB    = skA + (size_t)8 * MNA;                  // [16 * 384*512] sep0 splits
    float* scores8 = skB + (size_t)16 * MNA;                // [8 * MS]
    float* attw   = scores8 + 8 * MS;                       // [B,S]
    float* att4   = attw + MS;                              // [4,B,HID]
    float* ctx    = att4 + (size_t)4 * B_ * HID_;           // [B,HID]
    float* ctx2   = ctx + B_ * HID_;                        // [B,HID]
    float* havg   = ctx2 + B_ * HID_;                       // [B*K,EMB]
    int*   flag   = (int*)(havg + (size_t)B_ * K_ * EMB_);

    // 1. prep: weight transposes (bf16) + mask dtype probe
    prep<<<dim3(EMB_ / 32, HID_ / 32, 4), 256, 0, stream>>>(
        W_e2h, W_mm, W_a1, WtE2H, WtMM, WtA1, (const unsigned char*)masks, flag);

    // 2. ctx = relu(visual_context @ W_ctx + b_ctx)   [64,512], K=12288, split-K 64
    {
        const int nsp = 64, kps = (K_ * IMG_) / nsp;
        gemm_splitk<<<dim3(8, 1, nsp), 256, 0, stream>>>(vctx, W_ctx, skC,
                                                         B_, HID_, K_ * IMG_, kps);
        reduce_k<1><<<(B_ * HID_ + 255) / 256, 256, 0, stream>>>(skC, b_ctx, ctx,
                                                                 B_ * HID_, HID_, nsp);
    }
    // 3. ctx2 = ctx @ W_mm[H:,:] + b_mm               [64,512], K=512, split-K 8
    {
        const int nsp = 8, kps = HID_ / nsp;
        gemm_splitk<<<dim3(8, 1, nsp), 256, 0, stream>>>(ctx, W_mm + (size_t)HID_ * HID_,
                                                         skC, B_, HID_, HID_, kps);
        reduce_k<0><<<(B_ * HID_ + 255) / 256, 256, 0, stream>>>(skC, b_mm, ctx2,
                                                                 B_ * HID_, HID_, nsp);
    }

    const int big_grid = (MS_ / 128) * (HID_ / 128);   // 1024, % 8 == 0
    // 4. input_reps = relu(reps @ W_e2h + b_e2h)   fp32-in pipelined MFMA -> actA
    gemm_pipe<true, 1, false><<<big_grid, 256, 0, stream>>>(
        reps, WtE2H, b_e2h, nullptr, 1, actA, nullptr, nullptr, MS_, HID_, EMB_);
    // 5. mm = relu(input_reps @ W_mm[:H] + ctx2[b]) -> bf16 actB
    gemm_pipe<false, 1, false><<<big_grid, 256, 0, stream>>>(
        actA, WtMM, nullptr, ctx2, S_, actB, nullptr, nullptr, MS_, HID_, HID_);
    // 6. fused t=tanh(mm@W_a1+b_a1); scores8 = partial dots with W_a2
    gemm_pipe<false, 0, true><<<big_grid, 256, 0, stream>>>(
        actB, WtA1, b_a1, nullptr, 1, actA, W_a2, scores8, MS_, ATT_, HID_);
    // 7. masked softmax (sums 8 slots + b_a2) -> attw
    softmax8<<<B_, 256, 0, stream>>>(scores8, b_a2, masks, flag, attw);
    // 8. attended partials over 4 s-chunks
    attended4<<<dim3(B_, HID_ / 256, 4), 256, 0, stream>>>(actB, attw, att4);
    // 9. havg
    hist_avg<<<B_ * K_, 256, 0, stream>>>(phist, hcnt, havg);
    // 10. hproj partials                              [384,512], K=768, split-K 8
    gemm_splitk<<<dim3(8, 6, 8), 256, 0, stream>>>(havg, W_hist, skA,
                                                   B_ * K_, HID_, EMB_, EMB_ / 8);
    // 11. sep0 partials                               [384,512], K=2048, split-K 16
    gemm_splitk<<<dim3(8, 6, 16), 256, 0, stream>>>(sep_imgs, W_sep, skB,
                                                    B_ * K_, HID_, IMG_, IMG_ / 16);
    // 12. combine: reduce partials, relu/merge, L2-normalize, dot -> out [384]
    combine_all<<<B_ * K_, 256, 0, stream>>>(skA, skB, b_hist, b_sep, hcnt,
                                             att4, out);
}